// Round 1
// 485.877 us; speedup vs baseline: 1.0395x; 1.0395x over previous
//
#include <hip/hip_runtime.h>
#include <cstdint>
#include <cstddef>

typedef short short8 __attribute__((ext_vector_type(8)));
typedef float f32x4 __attribute__((ext_vector_type(4)));
typedef unsigned short us4 __attribute__((ext_vector_type(4)));

// ---------- helpers ----------
__device__ __forceinline__ unsigned short f2bf(float f) {
  unsigned int u = __float_as_uint(f);
  unsigned int r = (u + 0x7fffu + ((u >> 16) & 1u)) >> 16;  // RNE
  return (unsigned short)r;
}
// v_exp_f32: D = 2^S0 (builtin; __exp2f collides with glibc math.h here)
__device__ __forceinline__ float exp2_fast(float x) {
  return __builtin_amdgcn_exp2f(x);
}
// gfx950 packed f32->bf16 RNE convert: D[15:0]=bf16(a), D[31:16]=bf16(b)
__device__ __forceinline__ unsigned int cvt_pk_bf16(float a, float b) {
  unsigned int d;
  asm("v_cvt_pk_bf16_f32 %0, %1, %2" : "=v"(d) : "v"(a), "v"(b));
  return d;
}
// async global->LDS, 16B per lane. LDS dest = wave-uniform base + lane*16.
__device__ __forceinline__ void gload_lds16(const void* g, void* l) {
  auto gp = reinterpret_cast<const __attribute__((address_space(1))) char*>(
      reinterpret_cast<uintptr_t>(g));
  auto lp = reinterpret_cast<__attribute__((address_space(3))) char*>(
      reinterpret_cast<uintptr_t>(l));
  __builtin_amdgcn_global_load_lds(gp, lp, 16, 0, 0);
}

// ---------- weight reconstruction: w' = (LM@RM + W) * F * scale (bf16), b' = b*F*scale ----------
__global__ __launch_bounds__(256) void prep_weights(
    const float* __restrict__ W, const float* __restrict__ bias,
    const float* __restrict__ LM, const float* __restrict__ RM,
    const float* __restrict__ F, float scale,
    unsigned short* __restrict__ Wout, float* __restrict__ bout) {
  const int o = blockIdx.x;      // output row 0..1023
  const int tid = threadIdx.x;   // 256
  __shared__ float lm[64];
  if (tid < 64) lm[tid] = LM[o * 64 + tid];
  __syncthreads();
  const float f = F[o] * scale;
#pragma unroll
  for (int j = 0; j < 4; ++j) {
    const int i = tid + j * 256;
    float acc = W[o * 1024 + i];
#pragma unroll 16
    for (int k = 0; k < 64; ++k) acc = fmaf(lm[k], RM[k * 1024 + i], acc);
    Wout[o * 1024 + i] = f2bf(acc * f);
  }
  if (tid == 0) bout[o] = bias[o] * f;
}

// ---------- f32 -> bf16 cast ----------
__global__ __launch_bounds__(256) void cast_x(const float* __restrict__ x,
                                              unsigned short* __restrict__ y, int n4) {
  const int i = blockIdx.x * 256 + threadIdx.x;
  if (i >= n4) return;
  f32x4 v = *(const f32x4*)(x + (size_t)i * 4);
  us4 o;
  o[0] = f2bf(v[0]); o[1] = f2bf(v[1]); o[2] = f2bf(v[2]); o[3] = f2bf(v[3]);
  *(us4*)(y + (size_t)i * 4) = o;
}

// ---------- GEMM: C[m][n] = sum_k A[m][k]*Bw[n][k] + bias[n] ----------
// 128x128 block tile, BK=64, 4 waves each 64x64 (4x4 of 16x16x32 mfma).
// LDS XOR-swizzled: 16B chunk c of row r stored at chunk position c^(r&7).
// MODE 0: scatter to qkv bf16: q,k -> [bh][s][d]; v -> TRANSPOSED [bh][d][s].
// MODE 1: f32 row-major out.
template <int MODE>
__global__ __launch_bounds__(256) void gemm_bt(const unsigned short* __restrict__ A,
                                               const unsigned short* __restrict__ Bw,
                                               const float* __restrict__ bias,
                                               void* __restrict__ Cout,
                                               int M, int N, int K) {
  __shared__ unsigned short sA[128 * 64];
  __shared__ unsigned short sB[128 * 64];
  const int tid = threadIdx.x;
  const int w = tid >> 6;
  const int lane = tid & 63;
  const int quad = lane >> 4;
  const int ln = lane & 15;
  const int bm = blockIdx.x, bn = blockIdx.y;
  const int wm = w >> 1, wn = w & 1;

  f32x4 acc[4][4];
#pragma unroll
  for (int a = 0; a < 4; ++a)
#pragma unroll
    for (int b = 0; b < 4; ++b) acc[a][b] = (f32x4){0.f, 0.f, 0.f, 0.f};

  const size_t Kb = (size_t)K * 2;
  const char* Agb = (const char*)A + (size_t)bm * 128 * Kb;
  const char* Bgb = (const char*)Bw + (size_t)bn * 128 * Kb;
  char* sAb = (char*)sA;
  char* sBb = (char*)sB;
  const int sw = ln & 7;

  for (int k0 = 0; k0 < K; k0 += 64) {
    __syncthreads();  // LDS safe to overwrite
#pragma unroll
    for (int i = 0; i < 4; ++i) {
      const int Lb = w * 4096 + i * 1024 + lane * 16;  // linear byte in tile
      const int r = Lb >> 7;                           // tile row (128B rows)
      const int c = (Lb >> 4) & 7;                     // LDS chunk slot
      const int cb = ((c ^ (r & 7)) * 16);             // global chunk (unswizzle)
      gload_lds16(Agb + (size_t)r * Kb + (size_t)k0 * 2 + cb, sAb + Lb);
      gload_lds16(Bgb + (size_t)r * Kb + (size_t)k0 * 2 + cb, sBb + Lb);
    }
    __syncthreads();  // staging visible
#pragma unroll
    for (int kk = 0; kk < 2; ++kk) {
      short8 af[4], bfv[4];
#pragma unroll
      for (int t = 0; t < 4; ++t) {
        const int ch = ((kk * 4 + quad) ^ sw) * 16;
        af[t]  = *(const short8*)(sAb + (wm * 64 + t * 16 + ln) * 128 + ch);
        bfv[t] = *(const short8*)(sBb + (wn * 64 + t * 16 + ln) * 128 + ch);
      }
#pragma unroll
      for (int mt = 0; mt < 4; ++mt)
#pragma unroll
        for (int nt = 0; nt < 4; ++nt)
          acc[mt][nt] = __builtin_amdgcn_mfma_f32_16x16x32_bf16(af[mt], bfv[nt], acc[mt][nt], 0, 0, 0);
    }
  }

  // epilogue. C/D layout: col = ln, row = quad*4 + reg (measured m89/m91)
  if (MODE == 0) {
    unsigned short* out = (unsigned short*)Cout;
#pragma unroll
    for (int mt = 0; mt < 4; ++mt) {
#pragma unroll
      for (int nt = 0; nt < 4; ++nt) {
        const int gn = bn * 128 + wn * 64 + nt * 16 + ln;
        const float bv = bias[gn];
        const int pidx = gn >> 10, rem = gn & 1023;
        const int hh = rem >> 6, dd = rem & 63;
        const int gm0 = bm * 128 + wm * 64 + mt * 16 + quad * 4;
        const int bb = gm0 >> 10, ss0 = gm0 & 1023;
        if (pidx < 2) {
          // q,k: [p][b][h][s][d]
#pragma unroll
          for (int r = 0; r < 4; ++r) {
            const size_t off = ((((size_t)pidx * 16 + bb) * 16 + hh) * 1024 + (ss0 + r)) * 64 + dd;
            out[off] = f2bf(acc[mt][nt][r] + bv);
          }
        } else {
          // v: transposed [b][h][d][s]; r -> consecutive s -> one 8B store
          us4 pk;
#pragma unroll
          for (int r = 0; r < 4; ++r) pk[r] = f2bf(acc[mt][nt][r] + bv);
          const size_t off = (size_t)2 * 16777216 +
                             (((size_t)(bb * 16 + hh) * 64 + dd) * 1024 + ss0);
          *(us4*)(out + off) = pk;
        }
      }
    }
  } else {
    float* out = (float*)Cout;
#pragma unroll
    for (int mt = 0; mt < 4; ++mt) {
#pragma unroll
      for (int nt = 0; nt < 4; ++nt) {
        const int gn = bn * 128 + wn * 64 + nt * 16 + ln;
        const float bv = bias[gn];
#pragma unroll
        for (int r = 0; r < 4; ++r) {
          const int gm = bm * 128 + wm * 64 + mt * 16 + quad * 4 + r;
          out[(size_t)gm * N + gn] = acc[mt][nt][r] + bv;
        }
      }
    }
  }
}

// ---------- flash attention, S^T formulation, 2 q-subtiles per wave ----------
// R6 changes vs R5 baseline:
//  * K/V LDS double-buffered; staging for tile kt+1 issued BEFORE computing
//    tile kt; raw s_barrier + counted `s_waitcnt vmcnt(4)` so the 4 prefetch
//    loads stay in flight across the barrier (kills the per-tile full
//    vmcnt(0) drain that __syncthreads emits).  [T3/T4 minimum-2-phase]
//  * defer-max: skip the accO/lrun alpha-rescale when the new tile max is
//    within 8 (base-2) of the running max (P bounded by 2^8).  [T13]
//  * lrun kept as per-lane partial; cross-quad reduce moved to epilogue.
//  * s_setprio(1) around MFMA clusters.  [T5]
// Hazard notes:
//  - stage(kt+1) overwrites buf used by compute(kt-1); trailing barrier of
//    iter kt-1 orders that. vmcnt(4)+barrier at iter head => all waves'
//    stage(kt) landed before any ds_read of buf[cur].
//  - sP writes/reads are same-wave; DS ops are in-order per wave; explicit
//    compiler memory barrier forbids compile-time reordering.
__global__ __launch_bounds__(256) void attn(const unsigned short* __restrict__ Qb,
                                            const unsigned short* __restrict__ Kb_,
                                            const unsigned short* __restrict__ VTb,
                                            unsigned short* __restrict__ ctx) {
  __shared__ unsigned short sK[2][64 * 64];   // [buf][kv][d], 128B rows, swizzled
  __shared__ unsigned short sVT[2][64 * 64];  // [buf][d][kv], 128B rows, swizzled
  __shared__ unsigned short sP[128 * 72];     // [q][kv], 144B rows (pad 8 shorts)
  const int tid = threadIdx.x;
  const int w = tid >> 6, lane = tid & 63, quad = lane >> 4, ln = lane & 15;
  const int bid = blockIdx.x;
  const int xcd = bid & 7, qt = (bid >> 3) & 7, sbh = bid >> 6;
  const int bh = xcd * 32 + sbh;
  const int b = bh >> 4, h = bh & 15;

  char* sPb = (char*)sP;
  const int sw = ln & 7;

  // Q fragments (B-operand), loop-invariant: 2 subtiles x 2 k-halves
  short8 bq[2][2];
#pragma unroll
  for (int s = 0; s < 2; ++s) {
    const unsigned short* Qg =
        Qb + ((size_t)bh * 1024 + (size_t)qt * 128 + w * 32 + s * 16 + ln) * 64;
    bq[s][0] = *(const short8*)(Qg + quad * 8);
    bq[s][1] = *(const short8*)(Qg + 32 + quad * 8);
  }

  f32x4 accO[2][4];
#pragma unroll
  for (int s = 0; s < 2; ++s)
#pragma unroll
    for (int nt = 0; nt < 4; ++nt) accO[s][nt] = (f32x4){0.f, 0.f, 0.f, 0.f};
  float mrun[2] = {-3e38f, -3e38f}, lrun[2] = {0.f, 0.f};

  const char* Kbase = (const char*)Kb_ + (size_t)bh * 131072;  // [kv=1024][d=64] bf16
  const char* Vbase = (const char*)VTb + (size_t)bh * 131072;  // [d=64][kv=1024] bf16

  // issue 4 gload_lds (K,V interleaved) for tile kt into buffer buf
  auto stage = [&](int kt, int buf) {
#pragma unroll
    for (int i = 0; i < 2; ++i) {
      const int Lb = w * 2048 + i * 1024 + lane * 16;
      const int r = Lb >> 7;            // tile row (128B rows)
      const int c = (Lb >> 4) & 7;      // LDS chunk slot
      const int cb = ((c ^ (r & 7)) * 16);
      gload_lds16(Kbase + (size_t)kt * 8192 + (size_t)r * 128 + cb, (char*)sK[buf] + Lb);
      gload_lds16(Vbase + (size_t)kt * 128 + (size_t)r * 2048 + cb, (char*)sVT[buf] + Lb);
    }
  };

  stage(0, 0);  // prologue: 4 loads in flight

  for (int kt = 0; kt < 16; ++kt) {
    const int cur = kt & 1;
    char* sKb = (char*)sK[cur];
    char* sVb = (char*)sVT[cur];

    // prefetch next tile into the other buffer (wraps harmlessly at kt=15)
    stage((kt + 1) & 15, cur ^ 1);
    // wait for OWN stage(kt) (4 oldest of 8 outstanding); prefetch stays in flight
    asm volatile("s_waitcnt vmcnt(4)" ::: "memory");
    __builtin_amdgcn_s_barrier();  // all waves' stage(kt) landed
    asm volatile("" ::: "memory");

    // S^T = K Q^T : A = K (wave-uniform frags, reused for both subtiles)
    f32x4 accS[2][4];
#pragma unroll
    for (int s = 0; s < 2; ++s)
#pragma unroll
      for (int mt = 0; mt < 4; ++mt) accS[s][mt] = (f32x4){0.f, 0.f, 0.f, 0.f};
#pragma unroll
    for (int kk = 0; kk < 2; ++kk) {
      short8 ak[4];
#pragma unroll
      for (int mt = 0; mt < 4; ++mt)
        ak[mt] = *(const short8*)(sKb + (mt * 16 + ln) * 128 + ((kk * 4 + quad) ^ sw) * 16);
      __builtin_amdgcn_s_setprio(1);
#pragma unroll
      for (int s = 0; s < 2; ++s)
#pragma unroll
        for (int mt = 0; mt < 4; ++mt)
          accS[s][mt] = __builtin_amdgcn_mfma_f32_16x16x32_bf16(ak[mt], bq[s][kk], accS[s][mt], 0, 0, 0);
      __builtin_amdgcn_s_setprio(0);
    }

    // online softmax per subtile (base-2; q-logits pre-scaled by log2e).
    // Lane holds S[q = base + ln][kv = mt*16 + quad*4 + r].
#pragma unroll
    for (int s = 0; s < 2; ++s) {
      float tmax = -3e38f;
#pragma unroll
      for (int mt = 0; mt < 4; ++mt)
#pragma unroll
        for (int r = 0; r < 4; ++r) tmax = fmaxf(tmax, accS[s][mt][r]);
      tmax = fmaxf(tmax, __shfl_xor(tmax, 16));
      tmax = fmaxf(tmax, __shfl_xor(tmax, 32));
      // defer-max: only rescale when the tile max meaningfully exceeds mrun.
      if (!__all(tmax <= mrun[s] + 8.0f)) {
        const float mnew = fmaxf(mrun[s], tmax);
        const float alpha = exp2_fast(mrun[s] - mnew);
        mrun[s] = mnew;
        lrun[s] *= alpha;
#pragma unroll
        for (int r = 0; r < 4; ++r) {
          const float ar = __shfl(alpha, quad * 4 + r);
#pragma unroll
          for (int nt = 0; nt < 4; ++nt) accO[s][nt][r] *= ar;
        }
      }
      const float m = mrun[s];
      float psum = 0.f;
#pragma unroll
      for (int mt = 0; mt < 4; ++mt) {
        float p0 = exp2_fast(accS[s][mt][0] - m);
        float p1 = exp2_fast(accS[s][mt][1] - m);
        float p2 = exp2_fast(accS[s][mt][2] - m);
        float p3 = exp2_fast(accS[s][mt][3] - m);
        psum += (p0 + p1) + (p2 + p3);
        union { unsigned int u[2]; us4 v; } pu;
        pu.u[0] = cvt_pk_bf16(p0, p1);
        pu.u[1] = cvt_pk_bf16(p2, p3);
        *(us4*)(sP + (w * 32 + s * 16 + ln) * 72 + mt * 16 + quad * 4) = pu.v;  // 8B
      }
      lrun[s] += psum;  // per-lane partial; cross-quad reduce at epilogue
    }

    // Forbid hoisting the PV sP-reads above the softmax sP-writes.
    asm volatile("" ::: "memory");

    // O += P V : B = V^T (wave-uniform frags, reused for both subtiles)
#pragma unroll
    for (int kk = 0; kk < 2; ++kk) {
      short8 ap[2];
#pragma unroll
      for (int s = 0; s < 2; ++s)
        ap[s] = *(const short8*)(sPb + (w * 32 + s * 16 + ln) * 144 + kk * 64 + quad * 16);
#pragma unroll
      for (int nt = 0; nt < 4; ++nt) {
        const short8 bv = *(const short8*)(sVb + (nt * 16 + ln) * 128 + ((kk * 4 + quad) ^ sw) * 16);
        __builtin_amdgcn_s_setprio(1);
#pragma unroll
        for (int s = 0; s < 2; ++s)
          accO[s][nt] = __builtin_amdgcn_mfma_f32_16x16x32_bf16(ap[s], bv, accO[s][nt], 0, 0, 0);
        __builtin_amdgcn_s_setprio(0);
      }
    }

    __builtin_amdgcn_s_barrier();  // all waves done reading buf[cur]
    asm volatile("" ::: "memory");
  }

  // epilogue: ctx[b][s][h*64+d] bf16
#pragma unroll
  for (int s = 0; s < 2; ++s) {
    float l = lrun[s];
    l += __shfl_xor(l, 16);
    l += __shfl_xor(l, 32);
    const float inv = 1.0f / l;
#pragma unroll
    for (int r = 0; r < 4; ++r) {
      const float ivr = __shfl(inv, quad * 4 + r);
      const int sg = qt * 128 + w * 32 + s * 16 + quad * 4 + r;
#pragma unroll
      for (int nt = 0; nt < 4; ++nt) {
        const int d = nt * 16 + ln;
        ctx[((size_t)(b * 1024 + sg)) * 1024 + h * 64 + d] = f2bf(accO[s][nt][r] * ivr);
      }
    }
  }
}

// ---------- launch ----------
extern "C" void kernel_launch(void* const* d_in, const int* in_sizes, int n_in,
                              void* d_out, int out_size, void* d_ws, size_t ws_size,
                              hipStream_t stream) {
  const float* hs  = (const float*)d_in[0];
  const float* Wq  = (const float*)d_in[1];
  const float* bq  = (const float*)d_in[2];
  const float* LMq = (const float*)d_in[3];
  const float* RMq = (const float*)d_in[4];
  const float* Fq  = (const float*)d_in[5];
  const float* Wk  = (const float*)d_in[6];
  const float* bk  = (const float*)d_in[7];
  const float* LMk = (const float*)d_in[8];
  const float* RMk = (const float*)d_in[9];
  const float* Fk  = (const float*)d_in[10];
  const float* Wv  = (const float*)d_in[11];
  const float* bv  = (const float*)d_in[12];
  const float* LMv = (const float*)d_in[13];
  const float* RMv = (const float*)d_in[14];
  const float* Fv  = (const float*)d_in[15];
  const float* Wo  = (const float*)d_in[16];
  const float* bo  = (const float*)d_in[17];
  const float* LMo = (const float*)d_in[18];
  const float* RMo = (const float*)d_in[19];
  const float* Fo  = (const float*)d_in[20];
  // d_in[21] = task (always 0 branch in reference)

  // workspace layout (all 16B aligned)
  char* p = (char*)d_ws;
  unsigned short* xbf  = (unsigned short*)p; p += (size_t)16384 * 1024 * 2;   // 33.5 MB
  unsigned short* Wqkv = (unsigned short*)p; p += (size_t)3072 * 1024 * 2;    // 6.3 MB
  unsigned short* Wob  = (unsigned short*)p; p += (size_t)1024 * 1024 * 2;    // 2 MB
  float* bqkv = (float*)p; p += 3072 * 4;
  float* bob  = (float*)p; p += 1024 * 4;
  unsigned short* qkv = (unsigned short*)p; p += (size_t)3 * 16777216 * 2;    // 100.6 MB
  unsigned short* ctx = (unsigned short*)p; p += (size_t)16777216 * 2;        // 33.5 MB

  // 1/sqrt(64) * log2(e) folded into q weights+bias -> softmax in base 2
  const float qscale = 0.125f * 1.4426950408889634f;

  cast_x<<<16384, 256, 0, stream>>>(hs, xbf, 16777216 / 4);
  prep_weights<<<1024, 256, 0, stream>>>(Wq, bq, LMq, RMq, Fq, qscale, Wqkv, bqkv);
  prep_weights<<<1024, 256, 0, stream>>>(Wk, bk, LMk, RMk, Fk, 1.0f, Wqkv + 1024 * 1024, bqkv + 1024);
  prep_weights<<<1024, 256, 0, stream>>>(Wv, bv, LMv, RMv, Fv, 1.0f, Wqkv + 2 * 1024 * 1024, bqkv + 2048);
  prep_weights<<<1024, 256, 0, stream>>>(Wo, bo, LMo, RMo, Fo, 1.0f, Wob, bob);

  gemm_bt<0><<<dim3(128, 24), 256, 0, stream>>>(xbf, Wqkv, bqkv, (void*)qkv, 16384, 3072, 1024);

  attn<<<2048, 256, 0, stream>>>(qkv, qkv + 16777216, qkv + 2 * 16777216, ctx);

  gemm_bt<1><<<dim3(128, 8), 256, 0, stream>>>(ctx, Wob, bob, d_out, 16384, 1024, 1024);
}